// Round 20
// baseline (193.124 us; speedup 1.0000x reference)
//
#include <hip/hip_runtime.h>

typedef __bf16 bf16x8 __attribute__((ext_vector_type(8)));
typedef float f32x4 __attribute__((ext_vector_type(4)));
typedef unsigned short u16x8 __attribute__((ext_vector_type(8)));

#define BM 128
#define BN 128
#define BK 64

__device__ __forceinline__ unsigned short f2bf(float f) {
    union { float f; unsigned int u; } x; x.f = f;
    unsigned int u = x.u;
    u += 0x7fffu + ((u >> 16) & 1u);
    return (unsigned short)(u >> 16);
}

__device__ __forceinline__ float bf2f(unsigned short h) {
    union { unsigned int u; float f; } x; x.u = ((unsigned int)h) << 16;
    return x.f;
}

__device__ __forceinline__ void async_copy16(const void* g, void* l) {
    __builtin_amdgcn_global_load_lds(
        (const __attribute__((address_space(1))) void*)(uintptr_t)g,
        (__attribute__((address_space(3))) void*)(uintptr_t)l, 16, 0, 0);
}

// ---------------- conversion: x + wqkv gather (grid-stride) ----------------
// r17-verified variant (session best, 190.3 us total). Three later attempts
// (region-partition 32B chains, coalesced 16B chains) were all flat 53-55 us
// -> cvt is limited by something other than coalescing/MLP; keep verified.
__global__ void cvt_all(const float* __restrict__ x, const float* __restrict__ wq,
                        const float* __restrict__ wk, const float* __restrict__ wv,
                        const int* __restrict__ rep,
                        unsigned short* __restrict__ xb, unsigned short* __restrict__ wqkvb) {
    const long total = 3670016;
    long stride = (long)gridDim.x * 256;
    for (long i = (long)blockIdx.x * 256 + threadIdx.x; i < total; i += stride) {
        const float* src;
        unsigned short* dst;
        if (i < 524288) {
            src = x + i * 8;
            dst = xb + i * 8;
        } else {
            long j = i - 524288;
            int r = (int)(j >> 9), c8 = (int)(j & 511);
            const float* s;
            if (r < 1024)      s = wq + ((long)(rep[r >> 7] * 128 + (r & 127)) << 12);
            else if (r < 2048) s = wk + ((long)(rep[(r - 1024) >> 7] * 128 + (r & 127)) << 12);
            else               s = wv + ((long)(r - 2048) << 12);
            src = s + c8 * 8;
            dst = wqkvb + ((long)r << 12) + c8 * 8;
        }
        const f32x4* p4 = (const f32x4*)src;
        f32x4 v0 = p4[0];
        f32x4 v1 = p4[1];
        u16x8 o = { f2bf(v0[0]), f2bf(v0[1]), f2bf(v0[2]), f2bf(v0[3]),
                    f2bf(v1[0]), f2bf(v1[1]), f2bf(v1[2]), f2bf(v1[3]) };
        *(u16x8*)dst = o;
    }
}

// ---------------- GEMM bf16 x bf16: C[m][n] = sum_k A[m][k]*B[n][k] --------
// 128x128 tile, 4 waves, BK=64, XOR-swizzled LDS (conflicts=0, verified),
// SINGLE-BUFFER 32KB (r17 verified: 970 TF QKV at 3 blocks/CU; dbuf halved
// residency for no pipeline gain; counted-vmcnt/single-barrier/BK=32 all
// flat-to-worse). Loop: STAGE; __syncthreads; MFMA; __syncthreads.
// MODE: 0 = plain (split-K via kOffZ/kHead), 1 = scores (skip bn > bm tiles),
// 2 = PV causal (K limited to bm+BM), 3 = PV causal + wo f32->bf16 cvt blocks.
template<int MODE>
__global__ __launch_bounds__(256, 2) void gemm_bt(
    const unsigned short* __restrict__ A, const unsigned short* __restrict__ B,
    unsigned short* __restrict__ C, int K, int lda, int ldb, int ldc,
    long long aZ, long long bZ, long long cZ, const int* __restrict__ aIdx,
    int kOffZ, int kHead, int nby,
    const float* __restrict__ woF, unsigned short* __restrict__ wobD) {
    __shared__ unsigned short As[BM * BK];   // 16 KB
    __shared__ unsigned short Bs[BN * BK];   // 16 KB

    int L = blockIdx.x;
    if (MODE == 3 && L >= 256) {
        // wo conversion rider blocks: 512 blocks x 256 threads, 16 iters each
        int b = L - 256;
#pragma unroll
        for (int it = 0; it < 16; ++it) {
            long i = ((long)it * 512 + b) * 256 + threadIdx.x;   // 2097152
            const f32x4* p4 = (const f32x4*)(woF + i * 8);
            f32x4 v0 = p4[0];
            f32x4 v1 = p4[1];
            u16x8 o = { f2bf(v0[0]), f2bf(v0[1]), f2bf(v0[2]), f2bf(v0[3]),
                        f2bf(v1[0]), f2bf(v1[1]), f2bf(v1[2]), f2bf(v1[3]) };
            *(u16x8*)(wobD + i * 8) = o;
        }
        return;
    }

    int nblk = (MODE == 3) ? 256 : gridDim.x;
    int q8 = nblk >> 3;
    int wk_ = (L & 7) * q8 + (L >> 3);       // bijective XCD-chunk swizzle
    int bmi = wk_ & 7;
    int t2 = wk_ >> 3;
    int bni = t2 % nby;
    int z = t2 / nby;

    if (MODE == 1 && bni > bmi) return;

    A += (aIdx ? (long long)aIdx[z] : (long long)z) * aZ;
    B += (long long)z * bZ;
    int bm = bmi * BM;
    int bn = bni * BN;
    int t = threadIdx.x;
    int lane = t & 63;
    int w = t >> 6;
    int wr = (w >> 1) * 64, wc = (w & 1) * 64;

    int kt0 = (MODE == 0) ? z * kOffZ + (z > 0 ? kHead : 0) : 0;
    int kLen = (MODE >= 2) ? min(K, bm + BM)
                           : K + ((MODE == 0 && z == 0) ? kHead : 0);
    int kEnd = kt0 + kLen;

    f32x4 acc[4][4] = {};

    for (int kt = kt0; kt < kEnd; kt += BK) {
#pragma unroll
        for (int i = 0; i < 4; ++i) {
            int f = i * 256 + t;
            int row = f >> 3, c8 = f & 7;
            int cs = c8 ^ (row & 7);
            async_copy16(A + (long)(bm + row) * lda + kt + cs * 8, &As[f * 8]);
            async_copy16(B + (long)(bn + row) * ldb + kt + cs * 8, &Bs[f * 8]);
        }
        __syncthreads();   // drains vmcnt(0) lgkmcnt(0) + barrier (HIP semantics)
#pragma unroll
        for (int kk = 0; kk < BK; kk += 32) {
            bf16x8 a[4], b[4];
            int r0 = lane & 15;
            int kof = kk + ((lane >> 4) << 3);
            int kc = kof >> 3;
#pragma unroll
            for (int m = 0; m < 4; ++m) {
                int ra = wr + m * 16 + r0;
                a[m] = *(const bf16x8*)&As[ra * 64 + ((kc ^ (ra & 7)) << 3)];
            }
#pragma unroll
            for (int n = 0; n < 4; ++n) {
                int rb = wc + n * 16 + r0;
                b[n] = *(const bf16x8*)&Bs[rb * 64 + ((kc ^ (rb & 7)) << 3)];
            }
#pragma unroll
            for (int m = 0; m < 4; ++m)
#pragma unroll
                for (int n = 0; n < 4; ++n)
                    acc[m][n] = __builtin_amdgcn_mfma_f32_16x16x32_bf16(a[m], b[n], acc[m][n], 0, 0, 0);
        }
        __syncthreads();   // all waves done reading before next overwrite
    }

    int cl = lane & 15;
    int rbase = (lane >> 4) << 2;
    unsigned short* Cp = C + (long long)z * cZ;
#pragma unroll
    for (int m = 0; m < 4; ++m)
#pragma unroll
        for (int n = 0; n < 4; ++n)
#pragma unroll
            for (int j = 0; j < 4; ++j)
                Cp[(long)(bm + wr + m * 16 + rbase + j) * ldc + (bn + wc + n * 16 + cl)] = f2bf(acc[m][n][j]);
}

// ------- fused: reduce+RoPE (blocks 0-1023) | V transpose (blocks 1024+) ----
__global__ void rope_and_transpose(unsigned short* __restrict__ qkv,
                                   unsigned short* __restrict__ vt,
                                   const float* __restrict__ fc,
                                   const float* __restrict__ fs, int nsplit) {
    __shared__ unsigned short tile[32][33];
    int L = blockIdx.x;
    if (L < 1024) {
        int s = L;
        int cc = threadIdx.x * 8;
        long base = (long)s * 6144 + cc;
        ushort4 a0 = *(const ushort4*)(qkv + base);
        ushort4 a1 = *(const ushort4*)(qkv + base + 4);
        float f[8] = { bf2f(a0.x), bf2f(a0.y), bf2f(a0.z), bf2f(a0.w),
                       bf2f(a1.x), bf2f(a1.y), bf2f(a1.z), bf2f(a1.w) };
        if (nsplit == 2) {
            const unsigned short* p = qkv + 6291456;
            ushort4 b0 = *(const ushort4*)(p + base);
            ushort4 b1 = *(const ushort4*)(p + base + 4);
            f[0] += bf2f(b0.x); f[1] += bf2f(b0.y); f[2] += bf2f(b0.z); f[3] += bf2f(b0.w);
            f[4] += bf2f(b1.x); f[5] += bf2f(b1.y); f[6] += bf2f(b1.z); f[7] += bf2f(b1.w);
        }
        int i0 = (cc & 127) >> 1;
        const float* cp = fc + (s << 6) + i0;
        const float* sp = fs + (s << 6) + i0;
#pragma unroll
        for (int p = 0; p < 4; ++p) {
            float co = cp[p], sn = sp[p];
            float x0 = f[2 * p], x1 = f[2 * p + 1];
            f[2 * p] = x0 * co - x1 * sn;
            f[2 * p + 1] = x0 * sn + x1 * co;
        }
        ushort4 o0 = { f2bf(f[0]), f2bf(f[1]), f2bf(f[2]), f2bf(f[3]) };
        ushort4 o1 = { f2bf(f[4]), f2bf(f[5]), f2bf(f[6]), f2bf(f[7]) };
        *(ushort4*)(qkv + base) = o0;
        *(ushort4*)(qkv + base + 4) = o1;
    } else {
        int b = L - 1024;
        int h = b >> 7, s0 = ((b >> 2) & 31) * 32, d0 = (b & 3) * 32;
        int tx = threadIdx.x & 31, ty = threadIdx.x >> 5;
#pragma unroll
        for (int i = 0; i < 32; i += 8) {
            long idx = (long)(s0 + ty + i) * 6144 + 2048 + h * 128 + d0 + tx;
            float v = bf2f(qkv[idx]);
            if (nsplit == 2) v += bf2f(qkv[idx + 6291456]);
            tile[ty + i][tx] = f2bf(v);
        }
        __syncthreads();
#pragma unroll
        for (int i = 0; i < 32; i += 8)
            vt[(long)h * 131072 + (long)(d0 + ty + i) * 1024 + s0 + tx] = tile[tx][ty + i];
    }
}

// ---------------- out reduce: out = sum of 3 bf16 partials (f32 out) --------
__global__ void reduce_out3(const unsigned short* __restrict__ p, float* __restrict__ out) {
    long i = (long)blockIdx.x * 256 + threadIdx.x;
    ushort4 a = ((const ushort4*)p)[i];
    ushort4 b = ((const ushort4*)(p + 4194304))[i];
    ushort4 c = ((const ushort4*)(p + 8388608))[i];
    float4 o;
    o.x = bf2f(a.x) + bf2f(b.x) + bf2f(c.x);
    o.y = bf2f(a.y) + bf2f(b.y) + bf2f(c.y);
    o.z = bf2f(a.z) + bf2f(b.z) + bf2f(c.z);
    o.w = bf2f(a.w) + bf2f(b.w) + bf2f(c.w);
    ((float4*)out)[i] = o;
}

// ---------------- causal softmax: scores bf16 [8][1024][1024] -> P bf16 -----
__global__ __launch_bounds__(256) void softmax_causal(const unsigned short* __restrict__ sc,
                                                      unsigned short* __restrict__ P) {
    int i = blockIdx.x;
    int c = blockIdx.y;
    long base = ((long)c << 20) + ((long)i << 10);
    const unsigned short* row = sc + base;
    unsigned short* prow = P + base;
    int t = threadIdx.x;
    const float alpha = 0.08838834764831845f;  // 1/sqrt(128)
    int nj = i >> 8;

    float v[4];
    float mx = -3.4e38f;
    for (int j0 = 0; j0 <= nj; ++j0) {
        int j = j0 * 256 + t;
        float x = bf2f(row[j]) * alpha;
        v[j0] = (j <= i) ? x : -3.4e38f;
        mx = fmaxf(mx, v[j0]);
    }
#pragma unroll
    for (int o = 32; o > 0; o >>= 1) mx = fmaxf(mx, __shfl_xor(mx, o));
    __shared__ float red[4];
    int w = t >> 6, lane = t & 63;
    if (lane == 0) red[w] = mx;
    __syncthreads();
    mx = fmaxf(fmaxf(red[0], red[1]), fmaxf(red[2], red[3]));

    float e[4];
    float sum = 0.f;
    for (int j0 = 0; j0 <= nj; ++j0) {
        e[j0] = (v[j0] > -1e37f) ? __expf(v[j0] - mx) : 0.f;
        sum += e[j0];
    }
#pragma unroll
    for (int o = 32; o > 0; o >>= 1) sum += __shfl_xor(sum, o);
    __syncthreads();
    if (lane == 0) red[w] = sum;
    __syncthreads();
    sum = red[0] + red[1] + red[2] + red[3];
    float inv = 1.f / sum;
    for (int j0 = 0; j0 <= nj; ++j0) {
        int j = j0 * 256 + t;
        prow[j] = f2bf(e[j0] * inv);
    }
}

// ---------------- launch ----------------

extern "C" void kernel_launch(void* const* d_in, const int* in_sizes, int n_in,
                              void* d_out, int out_size, void* d_ws, size_t ws_size,
                              hipStream_t stream) {
    const float* x  = (const float*)d_in[0];
    const float* wq = (const float*)d_in[1];
    const float* wk = (const float*)d_in[2];
    const float* wv = (const float*)d_in[3];
    const float* wo = (const float*)d_in[4];
    const float* fc = (const float*)d_in[5];
    const float* fs = (const float*)d_in[6];
    const int* lab = (const int*)d_in[8];   // cluster_assignment [32]
    const int* rep = (const int*)d_in[9];   // rep_heads [8]
    float* out = (float*)d_out;

    char* ws = (char*)d_ws;
    unsigned short* xb    = (unsigned short*)(ws);                // 0-8 MiB; later attn
    unsigned short* wqkvb = (unsigned short*)(ws + 8388608);      // 8-56 MiB
    unsigned short* wob   = (unsigned short*)(ws + 58720256);     // 56-88 MiB
    unsigned short* qkv_s = (unsigned short*)(ws + 92274688);     // 88-100 MiB [1024][6144]
    // QKV split-K partial z=1: 100-112 MiB. vt must NOT alias it (r10-12 bug).
    // vt at 24-32 MiB: scores (8-24) dead after step 5; opart (8-32, 3
    // partials) written only at step 7, after vt's last read (step 6).
    unsigned short* vt    = (unsigned short*)(ws + 25165824);     // 24-32 MiB
    unsigned short* scores= (unsigned short*)(ws + 8388608);      // 8-24 MiB bf16
    unsigned short* P     = (unsigned short*)(ws + 41943040);     // 40-56 MiB
    unsigned short* opart = (unsigned short*)(ws + 8388608);      // 8-32 MiB (3 partials)
    unsigned short* attn  = xb;                                   // [1024][4096] bf16

    int skQ = (ws_size >= (size_t)117440512) ? 2 : 1;

    // 1. bf16 conversions: x + wqkv gather (wo is converted inside PV kernel)
    cvt_all<<<2048, 256, 0, stream>>>(x, wq, wk, wv, rep, xb, wqkvb);

    // 2. QKV projection: qkv_s[1024][6144] = xb @ wqkvb^T (split-K=2, bf16 partials)
    if (skQ == 2) {
        gemm_bt<0><<<768, 256, 0, stream>>>(
            xb, wqkvb, qkv_s, 2048, 4096, 4096, 6144, 0, 0, 6291456, nullptr,
            2048, 0, 48, nullptr, nullptr);
    } else {
        gemm_bt<0><<<384, 256, 0, stream>>>(
            xb, wqkvb, qkv_s, 4096, 4096, 4096, 6144, 0, 0, 0, nullptr,
            0, 0, 48, nullptr, nullptr);
    }

    // 3. fused: split-K reduce + RoPE (Q/K) | V transpose (+its own reduce)
    rope_and_transpose<<<5120, 256, 0, stream>>>(qkv_s, vt, fc, fs, skQ);

    // 4. scores[c] = Q_rep_c @ K_rep_c^T  (lower-triangle tiles only, bf16 out)
    gemm_bt<1><<<512, 256, 0, stream>>>(
        qkv_s, qkv_s + 1024, scores, 128, 6144, 6144, 1024,
        128, 128, 1048576, nullptr, 0, 0, 8, nullptr, nullptr);

    // 5. causal softmax -> P bf16
    softmax_causal<<<dim3(1024, 8), 256, 0, stream>>>(scores, P);

    // 6. attn = P[lab[h]] @ V_h (256 blocks) + 512 wo-cvt rider blocks
    gemm_bt<3><<<768, 256, 0, stream>>>(
        P, vt, attn, 1024, 1024, 1024, 4096,
        1048576, 131072, 128, lab, 0, 0, 1, wo, wob);

    // 7. out = attn @ wo^T  (split-K=3 uneven 1408/1344/1344, bf16 partials)
    gemm_bt<0><<<768, 256, 0, stream>>>(
        attn, wob, opart, 1344, 4096, 4096, 4096, 0, 0, 4194304, nullptr,
        1344, 64, 32, nullptr, nullptr);
    reduce_out3<<<4096, 256, 0, stream>>>(opart, out);
}

// Round 21
// 188.364 us; speedup vs baseline: 1.0253x; 1.0253x over previous
//
#include <hip/hip_runtime.h>

typedef __bf16 bf16x8 __attribute__((ext_vector_type(8)));
typedef float f32x4 __attribute__((ext_vector_type(4)));
typedef unsigned short u16x8 __attribute__((ext_vector_type(8)));

#define BM 128
#define BN 128
#define BK 64

__device__ __forceinline__ unsigned short f2bf(float f) {
    union { float f; unsigned int u; } x; x.f = f;
    unsigned int u = x.u;
    u += 0x7fffu + ((u >> 16) & 1u);
    return (unsigned short)(u >> 16);
}

__device__ __forceinline__ float bf2f(unsigned short h) {
    union { unsigned int u; float f; } x; x.u = ((unsigned int)h) << 16;
    return x.f;
}

__device__ __forceinline__ void async_copy16(const void* g, void* l) {
    __builtin_amdgcn_global_load_lds(
        (const __attribute__((address_space(1))) void*)(uintptr_t)g,
        (__attribute__((address_space(3))) void*)(uintptr_t)l, 16, 0, 0);
}

// ---------------- conversion: x + wqkv gather (grid-stride) ----------------
// r17-verified variant (session best). Three alternative structures
// (region-partition 32B chains, coalesced 16B chains) all flat 53-55 us.
__global__ void cvt_all(const float* __restrict__ x, const float* __restrict__ wq,
                        const float* __restrict__ wk, const float* __restrict__ wv,
                        const int* __restrict__ rep,
                        unsigned short* __restrict__ xb, unsigned short* __restrict__ wqkvb) {
    const long total = 3670016;
    long stride = (long)gridDim.x * 256;
    for (long i = (long)blockIdx.x * 256 + threadIdx.x; i < total; i += stride) {
        const float* src;
        unsigned short* dst;
        if (i < 524288) {
            src = x + i * 8;
            dst = xb + i * 8;
        } else {
            long j = i - 524288;
            int r = (int)(j >> 9), c8 = (int)(j & 511);
            const float* s;
            if (r < 1024)      s = wq + ((long)(rep[r >> 7] * 128 + (r & 127)) << 12);
            else if (r < 2048) s = wk + ((long)(rep[(r - 1024) >> 7] * 128 + (r & 127)) << 12);
            else               s = wv + ((long)(r - 2048) << 12);
            src = s + c8 * 8;
            dst = wqkvb + ((long)r << 12) + c8 * 8;
        }
        const f32x4* p4 = (const f32x4*)src;
        f32x4 v0 = p4[0];
        f32x4 v1 = p4[1];
        u16x8 o = { f2bf(v0[0]), f2bf(v0[1]), f2bf(v0[2]), f2bf(v0[3]),
                    f2bf(v1[0]), f2bf(v1[1]), f2bf(v1[2]), f2bf(v1[3]) };
        *(u16x8*)dst = o;
    }
}

// ---------------- GEMM bf16 x bf16: C[m][n] = sum_k A[m][k]*B[n][k] --------
// 128x128 tile, 4 waves, BK=64, XOR-swizzled LDS (conflicts=0, verified),
// SINGLE-BUFFER 32KB (r17 verified: 970 TF QKV at 3 blocks/CU; dbuf halved
// residency for no pipeline gain; counted-vmcnt/single-barrier/BK=32 all
// flat-to-worse). Loop: STAGE; __syncthreads; MFMA; __syncthreads.
// MODE: 0 = plain (split-K via kOffZ/kHead), 1 = scores (skip bn > bm tiles),
// 2 = PV causal (K limited to bm+BM), 3 = PV causal + wo f32->bf16 cvt blocks.
template<int MODE>
__global__ __launch_bounds__(256, 2) void gemm_bt(
    const unsigned short* __restrict__ A, const unsigned short* __restrict__ B,
    unsigned short* __restrict__ C, int K, int lda, int ldb, int ldc,
    long long aZ, long long bZ, long long cZ, const int* __restrict__ aIdx,
    int kOffZ, int kHead, int nby,
    const float* __restrict__ woF, unsigned short* __restrict__ wobD) {
    __shared__ unsigned short As[BM * BK];   // 16 KB
    __shared__ unsigned short Bs[BN * BK];   // 16 KB

    int L = blockIdx.x;
    if (MODE == 3 && L >= 256) {
        // wo conversion rider blocks: 512 blocks x 256 threads, 16 iters each
        int b = L - 256;
#pragma unroll
        for (int it = 0; it < 16; ++it) {
            long i = ((long)it * 512 + b) * 256 + threadIdx.x;   // 2097152
            const f32x4* p4 = (const f32x4*)(woF + i * 8);
            f32x4 v0 = p4[0];
            f32x4 v1 = p4[1];
            u16x8 o = { f2bf(v0[0]), f2bf(v0[1]), f2bf(v0[2]), f2bf(v0[3]),
                        f2bf(v1[0]), f2bf(v1[1]), f2bf(v1[2]), f2bf(v1[3]) };
            *(u16x8*)(wobD + i * 8) = o;
        }
        return;
    }

    int nblk = (MODE == 3) ? 256 : gridDim.x;
    int q8 = nblk >> 3;
    int wk_ = (L & 7) * q8 + (L >> 3);       // bijective XCD-chunk swizzle
    int bmi = wk_ & 7;
    int t2 = wk_ >> 3;
    int bni = t2 % nby;
    int z = t2 / nby;

    if (MODE == 1 && bni > bmi) return;

    A += (aIdx ? (long long)aIdx[z] : (long long)z) * aZ;
    B += (long long)z * bZ;
    int bm = bmi * BM;
    int bn = bni * BN;
    int t = threadIdx.x;
    int lane = t & 63;
    int w = t >> 6;
    int wr = (w >> 1) * 64, wc = (w & 1) * 64;

    int kt0 = (MODE == 0) ? z * kOffZ + (z > 0 ? kHead : 0) : 0;
    int kLen = (MODE >= 2) ? min(K, bm + BM)
                           : K + ((MODE == 0 && z == 0) ? kHead : 0);
    int kEnd = kt0 + kLen;

    f32x4 acc[4][4] = {};

    for (int kt = kt0; kt < kEnd; kt += BK) {
#pragma unroll
        for (int i = 0; i < 4; ++i) {
            int f = i * 256 + t;
            int row = f >> 3, c8 = f & 7;
            int cs = c8 ^ (row & 7);
            async_copy16(A + (long)(bm + row) * lda + kt + cs * 8, &As[f * 8]);
            async_copy16(B + (long)(bn + row) * ldb + kt + cs * 8, &Bs[f * 8]);
        }
        __syncthreads();   // drains vmcnt(0) lgkmcnt(0) + barrier (HIP semantics)
#pragma unroll
        for (int kk = 0; kk < BK; kk += 32) {
            bf16x8 a[4], b[4];
            int r0 = lane & 15;
            int kof = kk + ((lane >> 4) << 3);
            int kc = kof >> 3;
#pragma unroll
            for (int m = 0; m < 4; ++m) {
                int ra = wr + m * 16 + r0;
                a[m] = *(const bf16x8*)&As[ra * 64 + ((kc ^ (ra & 7)) << 3)];
            }
#pragma unroll
            for (int n = 0; n < 4; ++n) {
                int rb = wc + n * 16 + r0;
                b[n] = *(const bf16x8*)&Bs[rb * 64 + ((kc ^ (rb & 7)) << 3)];
            }
#pragma unroll
            for (int m = 0; m < 4; ++m)
#pragma unroll
                for (int n = 0; n < 4; ++n)
                    acc[m][n] = __builtin_amdgcn_mfma_f32_16x16x32_bf16(a[m], b[n], acc[m][n], 0, 0, 0);
        }
        __syncthreads();   // all waves done reading before next overwrite
    }

    int cl = lane & 15;
    int rbase = (lane >> 4) << 2;
    unsigned short* Cp = C + (long long)z * cZ;
#pragma unroll
    for (int m = 0; m < 4; ++m)
#pragma unroll
        for (int n = 0; n < 4; ++n)
#pragma unroll
            for (int j = 0; j < 4; ++j)
                Cp[(long)(bm + wr + m * 16 + rbase + j) * ldc + (bn + wc + n * 16 + cl)] = f2bf(acc[m][n][j]);
}

// ------- fused: reduce+RoPE (blocks 0-1023) | V transpose (blocks 1024+) ----
__global__ void rope_and_transpose(unsigned short* __restrict__ qkv,
                                   unsigned short* __restrict__ vt,
                                   const float* __restrict__ fc,
                                   const float* __restrict__ fs, int nsplit) {
    __shared__ unsigned short tile[32][33];
    int L = blockIdx.x;
    if (L < 1024) {
        int s = L;
        int cc = threadIdx.x * 8;
        long base = (long)s * 6144 + cc;
        ushort4 a0 = *(const ushort4*)(qkv + base);
        ushort4 a1 = *(const ushort4*)(qkv + base + 4);
        float f[8] = { bf2f(a0.x), bf2f(a0.y), bf2f(a0.z), bf2f(a0.w),
                       bf2f(a1.x), bf2f(a1.y), bf2f(a1.z), bf2f(a1.w) };
        if (nsplit == 2) {
            const unsigned short* p = qkv + 6291456;
            ushort4 b0 = *(const ushort4*)(p + base);
            ushort4 b1 = *(const ushort4*)(p + base + 4);
            f[0] += bf2f(b0.x); f[1] += bf2f(b0.y); f[2] += bf2f(b0.z); f[3] += bf2f(b0.w);
            f[4] += bf2f(b1.x); f[5] += bf2f(b1.y); f[6] += bf2f(b1.z); f[7] += bf2f(b1.w);
        }
        int i0 = (cc & 127) >> 1;
        const float* cp = fc + (s << 6) + i0;
        const float* sp = fs + (s << 6) + i0;
#pragma unroll
        for (int p = 0; p < 4; ++p) {
            float co = cp[p], sn = sp[p];
            float x0 = f[2 * p], x1 = f[2 * p + 1];
            f[2 * p] = x0 * co - x1 * sn;
            f[2 * p + 1] = x0 * sn + x1 * co;
        }
        ushort4 o0 = { f2bf(f[0]), f2bf(f[1]), f2bf(f[2]), f2bf(f[3]) };
        ushort4 o1 = { f2bf(f[4]), f2bf(f[5]), f2bf(f[6]), f2bf(f[7]) };
        *(ushort4*)(qkv + base) = o0;
        *(ushort4*)(qkv + base + 4) = o1;
    } else {
        int b = L - 1024;
        int h = b >> 7, s0 = ((b >> 2) & 31) * 32, d0 = (b & 3) * 32;
        int tx = threadIdx.x & 31, ty = threadIdx.x >> 5;
#pragma unroll
        for (int i = 0; i < 32; i += 8) {
            long idx = (long)(s0 + ty + i) * 6144 + 2048 + h * 128 + d0 + tx;
            float v = bf2f(qkv[idx]);
            if (nsplit == 2) v += bf2f(qkv[idx + 6291456]);
            tile[ty + i][tx] = f2bf(v);
        }
        __syncthreads();
#pragma unroll
        for (int i = 0; i < 32; i += 8)
            vt[(long)h * 131072 + (long)(d0 + ty + i) * 1024 + s0 + tx] = tile[tx][ty + i];
    }
}

// ---------------- out reduce: out = sum of 3 bf16 partials (f32 out) --------
__global__ void reduce_out3(const unsigned short* __restrict__ p, float* __restrict__ out) {
    long i = (long)blockIdx.x * 256 + threadIdx.x;
    ushort4 a = ((const ushort4*)p)[i];
    ushort4 b = ((const ushort4*)(p + 4194304))[i];
    ushort4 c = ((const ushort4*)(p + 8388608))[i];
    float4 o;
    o.x = bf2f(a.x) + bf2f(b.x) + bf2f(c.x);
    o.y = bf2f(a.y) + bf2f(b.y) + bf2f(c.y);
    o.z = bf2f(a.z) + bf2f(b.z) + bf2f(c.z);
    o.w = bf2f(a.w) + bf2f(b.w) + bf2f(c.w);
    ((float4*)out)[i] = o;
}

// ---------------- causal softmax: scores bf16 [8][1024][1024] -> P bf16 -----
// r21: vectorized (G13). Thread t owns contiguous elems [4t, 4t+4): ushort4
// load if 4t <= i (else all-masked), ushort4 store if 4t <= (i|127) — writes
// zeros through the PV tile boundary bm+128, exactly the coverage PV reads
// (same as the old 256-chunk loop). Reductions over the same element set.
__global__ __launch_bounds__(256) void softmax_causal(const unsigned short* __restrict__ sc,
                                                      unsigned short* __restrict__ P) {
    int i = blockIdx.x;
    int c = blockIdx.y;
    long base = ((long)c << 20) + ((long)i << 10);
    int t = threadIdx.x;
    const float alpha = 0.08838834764831845f;  // 1/sqrt(128)
    int j0 = t * 4;
    bool activeLoad = (j0 <= i);
    bool activeStore = (j0 <= (i | 127));

    float v[4];
    float mx = -3.4e38f;
    if (activeLoad) {
        ushort4 r = *(const ushort4*)(sc + base + j0);
        unsigned short rr[4] = { r.x, r.y, r.z, r.w };
#pragma unroll
        for (int k = 0; k < 4; ++k) {
            float xv = bf2f(rr[k]) * alpha;
            v[k] = (j0 + k <= i) ? xv : -3.4e38f;
            mx = fmaxf(mx, v[k]);
        }
    } else {
        v[0] = v[1] = v[2] = v[3] = -3.4e38f;
    }
#pragma unroll
    for (int o = 32; o > 0; o >>= 1) mx = fmaxf(mx, __shfl_xor(mx, o));
    __shared__ float red[4];
    int w = t >> 6, lane = t & 63;
    if (lane == 0) red[w] = mx;
    __syncthreads();
    mx = fmaxf(fmaxf(red[0], red[1]), fmaxf(red[2], red[3]));

    float e[4] = { 0.f, 0.f, 0.f, 0.f };
    float sum = 0.f;
    if (activeLoad) {
#pragma unroll
        for (int k = 0; k < 4; ++k) {
            e[k] = (v[k] > -1e37f) ? __expf(v[k] - mx) : 0.f;
            sum += e[k];
        }
    }
#pragma unroll
    for (int o = 32; o > 0; o >>= 1) sum += __shfl_xor(sum, o);
    __syncthreads();
    if (lane == 0) red[w] = sum;
    __syncthreads();
    sum = red[0] + red[1] + red[2] + red[3];
    float inv = 1.f / sum;
    if (activeStore) {
        ushort4 o4 = { f2bf(e[0] * inv), f2bf(e[1] * inv),
                       f2bf(e[2] * inv), f2bf(e[3] * inv) };
        *(ushort4*)(P + base + j0) = o4;
    }
}

// ---------------- launch ----------------

extern "C" void kernel_launch(void* const* d_in, const int* in_sizes, int n_in,
                              void* d_out, int out_size, void* d_ws, size_t ws_size,
                              hipStream_t stream) {
    const float* x  = (const float*)d_in[0];
    const float* wq = (const float*)d_in[1];
    const float* wk = (const float*)d_in[2];
    const float* wv = (const float*)d_in[3];
    const float* wo = (const float*)d_in[4];
    const float* fc = (const float*)d_in[5];
    const float* fs = (const float*)d_in[6];
    const int* lab = (const int*)d_in[8];   // cluster_assignment [32]
    const int* rep = (const int*)d_in[9];   // rep_heads [8]
    float* out = (float*)d_out;

    char* ws = (char*)d_ws;
    unsigned short* xb    = (unsigned short*)(ws);                // 0-8 MiB; later attn
    unsigned short* wqkvb = (unsigned short*)(ws + 8388608);      // 8-56 MiB
    unsigned short* wob   = (unsigned short*)(ws + 58720256);     // 56-88 MiB
    unsigned short* qkv_s = (unsigned short*)(ws + 92274688);     // 88-100 MiB [1024][6144]
    // QKV split-K partial z=1: 100-112 MiB. vt must NOT alias it (r10-12 bug).
    // vt at 24-32 MiB: scores (8-24) dead after step 5; opart (8-32, 3
    // partials) written only at step 7, after vt's last read (step 6).
    unsigned short* vt    = (unsigned short*)(ws + 25165824);     // 24-32 MiB
    unsigned short* scores= (unsigned short*)(ws + 8388608);      // 8-24 MiB bf16
    unsigned short* P     = (unsigned short*)(ws + 41943040);     // 40-56 MiB
    unsigned short* opart = (unsigned short*)(ws + 8388608);      // 8-32 MiB (3 partials)
    unsigned short* attn  = xb;                                   // [1024][4096] bf16

    int skQ = (ws_size >= (size_t)117440512) ? 2 : 1;

    // 1. bf16 conversions: x + wqkv gather (wo is converted inside PV kernel)
    cvt_all<<<2048, 256, 0, stream>>>(x, wq, wk, wv, rep, xb, wqkvb);

    // 2. QKV projection: qkv_s[1024][6144] = xb @ wqkvb^T (split-K=2, bf16 partials)
    if (skQ == 2) {
        gemm_bt<0><<<768, 256, 0, stream>>>(
            xb, wqkvb, qkv_s, 2048, 4096, 4096, 6144, 0, 0, 6291456, nullptr,
            2048, 0, 48, nullptr, nullptr);
    } else {
        gemm_bt<0><<<384, 256, 0, stream>>>(
            xb, wqkvb, qkv_s, 4096, 4096, 4096, 6144, 0, 0, 0, nullptr,
            0, 0, 48, nullptr, nullptr);
    }

    // 3. fused: split-K reduce + RoPE (Q/K) | V transpose (+its own reduce)
    rope_and_transpose<<<5120, 256, 0, stream>>>(qkv_s, vt, fc, fs, skQ);

    // 4. scores[c] = Q_rep_c @ K_rep_c^T  (lower-triangle tiles only, bf16 out)
    gemm_bt<1><<<512, 256, 0, stream>>>(
        qkv_s, qkv_s + 1024, scores, 128, 6144, 6144, 1024,
        128, 128, 1048576, nullptr, 0, 0, 8, nullptr, nullptr);

    // 5. causal softmax -> P bf16 (vectorized)
    softmax_causal<<<dim3(1024, 8), 256, 0, stream>>>(scores, P);

    // 6. attn = P[lab[h]] @ V_h (256 blocks) + 512 wo-cvt rider blocks
    gemm_bt<3><<<768, 256, 0, stream>>>(
        P, vt, attn, 1024, 1024, 1024, 4096,
        1048576, 131072, 128, lab, 0, 0, 1, wo, wob);

    // 7. out = attn @ wo^T  (split-K=3 uneven 1408/1344/1344, bf16 partials)
    gemm_bt<0><<<768, 256, 0, stream>>>(
        attn, wob, opart, 1344, 4096, 4096, 4096, 0, 0, 4194304, nullptr,
        1344, 64, 32, nullptr, nullptr);
    reduce_out3<<<4096, 256, 0, stream>>>(opart, out);
}